// Round 4
// baseline (102.008 us; speedup 1.0000x reference)
//
#include <hip/hip_runtime.h>

#define N_ATOMS 20000
#define BATCH   16
#define N_BONDS 60000
#define NDIR    (2 * N_BONDS)
#define NB      (N_ATOMS * BATCH)      // 320000

// Workspace layout (int-indexed):
//   deg[20000] | offsets[20001] | cursor | adj[120000] | Mc[12]
//   posT[N][16][4] floats (node-major, padded float4)  | h2T same
#define OFF_DEG     0
#define OFF_OFFSETS 20000
#define OFF_CURSOR  40004
#define OFF_ADJ     60004
#define OFF_MC      180004
#define OFF_POST    180032                 // 16B aligned
#define OFF_H2T     (OFF_POST + NB * 4)    // 16B aligned

#define TRANS_BLOCKS 1250   // 1250*256 = 320000 = N*B
#define DEG_BLOCKS   235    // ceil(60000/256)

__global__ void zero_deg_kernel(int4* __restrict__ deg4) {
    int i = blockIdx.x * blockDim.x + threadIdx.x;
    if (i < N_ATOMS / 4) deg4[i] = make_int4(0, 0, 0, 0);
}

// blocks [0,1250): transpose positions[B][N][3] -> posT[N][16][4] (b-fastest lanes,
//                  256B-contiguous writes per node). blocks [1250,1485): degree count.
__global__ void deg_transpose_kernel(const int* __restrict__ bonds, int* __restrict__ deg,
                                     const float* __restrict__ pos, float4* __restrict__ posT) {
    int blk = blockIdx.x;
    if (blk < TRANS_BLOCKS) {
        int t = blk * 256 + threadIdx.x;        // 0..319999
        int b = t & 15, n = t >> 4;
        const float* p = pos + ((size_t)b * N_ATOMS + n) * 3;
        posT[n * 16 + b] = make_float4(p[0], p[1], p[2], 0.0f);
    } else {
        int e = (blk - TRANS_BLOCKS) * 256 + threadIdx.x;
        if (e < N_BONDS) {
            atomicAdd(&deg[bonds[2 * e]], 1);
            atomicAdd(&deg[bonds[2 * e + 1]], 1);
        }
    }
}

// block 0: exclusive scan of deg -> offsets/cursor (256 threads x 79-chunk).
// block 1: Mc = [W_msg @ W_upd (9) ; b_msg @ W_upd (3)].
__global__ void scan_mc_kernel(const int* __restrict__ deg, int* __restrict__ offsets,
                               int* __restrict__ cursor,
                               const float* __restrict__ W_msg, const float* __restrict__ b_msg,
                               const float* __restrict__ W_upd, float* __restrict__ Mc) {
    if (blockIdx.x == 1) {
        int t = threadIdx.x;
        if (t < 12) {
            float s = 0.0f;
            if (t < 9) {
                int i = t / 3, j = t % 3;
                for (int k = 0; k < 128; ++k) s += W_msg[i * 128 + k] * W_upd[k * 3 + j];
            } else {
                int j = t - 9;
                for (int k = 0; k < 128; ++k) s += b_msg[k] * W_upd[k * 3 + j];
            }
            Mc[t] = s;
        }
        return;
    }
    __shared__ int sums[256];
    const int CH = 79;                       // 256*79 = 20224 >= 20000
    int t = threadIdx.x;
    int beg = t * CH;
    int run = 0;
    for (int k = 0; k < CH; ++k) {
        int i = beg + k;
        if (i < N_ATOMS) run += deg[i];
    }
    sums[t] = run;
    __syncthreads();
    int acc = run;
    for (int off = 1; off < 256; off <<= 1) {
        int v = (t >= off) ? sums[t - off] : 0;
        __syncthreads();
        acc += v;
        sums[t] = acc;
        __syncthreads();
    }
    int running = acc - run;                 // exclusive prefix of this chunk
    for (int k = 0; k < CH; ++k) {
        int i = beg + k;
        if (i < N_ATOMS) {
            offsets[i] = running;
            cursor[i] = running;
            running += deg[i];               // deg re-read: L1-hit
        }
    }
    if (t == 255) offsets[N_ATOMS] = acc;
}

__global__ void fill_adj_kernel(const int* __restrict__ bonds, int* __restrict__ cursor,
                                int* __restrict__ adj) {
    int e = blockIdx.x * blockDim.x + threadIdx.x;
    if (e >= N_BONDS) return;
    int a0 = bonds[2 * e];
    int a1 = bonds[2 * e + 1];
    int p1 = atomicAdd(&cursor[a1], 1);
    adj[p1] = a0;
    int p0 = atomicAdd(&cursor[a0], 1);
    adj[p0] = a1;
}

// Node-major fused iteration. Block = 16 nodes x 16 batches (b fastest), so the
// 16 lanes of a node-group gather the SAME neighbor j as one contiguous 256B read.
// FINAL=false: write hT-layout float4. FINAL=true: re-transpose via padded LDS and
// write packed out[B][N][3].
template <bool FINAL>
__global__ __launch_bounds__(256) void gather_kernel(const float4* __restrict__ hT,
                                                     const int* __restrict__ offsets,
                                                     const int* __restrict__ adj,
                                                     const float* __restrict__ Mc,
                                                     const float* __restrict__ b_upd,
                                                     float4* __restrict__ outT,
                                                     float* __restrict__ outP) {
    __shared__ float lds[16 * 51];           // stride 51: conflict-free re-transpose
    int t = threadIdx.x;
    int b = t & 15;
    int nl = t >> 4;
    int n = blockIdx.x * 16 + nl;            // 1250*16 = 20000 exactly
    int beg = offsets[n], end = offsets[n + 1];
    float sx = 0.0f, sy = 0.0f, sz = 0.0f;
    for (int k = beg; k < end; ++k) {
        int j = adj[k];                      // group-uniform -> broadcast
        float4 v = hT[j * 16 + b];           // 16 lanes = 256B contiguous
        sx += v.x; sy += v.y; sz += v.z;
    }
    float4 me = hT[n * 16 + b];
    int d = end - beg;
    float inv = d > 0 ? 1.0f / (float)d : 0.0f;
    float flag = d > 0 ? 1.0f : 0.0f;
    float o0 = me.x + inv * (sx * Mc[0] + sy * Mc[3] + sz * Mc[6]) + flag * Mc[9]  + b_upd[0];
    float o1 = me.y + inv * (sx * Mc[1] + sy * Mc[4] + sz * Mc[7]) + flag * Mc[10] + b_upd[1];
    float o2 = me.z + inv * (sx * Mc[2] + sy * Mc[5] + sz * Mc[8]) + flag * Mc[11] + b_upd[2];
    if (!FINAL) {
        outT[n * 16 + b] = make_float4(o0, o1, o2, 0.0f);
    } else {
        lds[nl * 51 + b * 3 + 0] = o0;
        lds[nl * 51 + b * 3 + 1] = o1;
        lds[nl * 51 + b * 3 + 2] = o2;
        __syncthreads();
        int b2 = t >> 4, n2 = t & 15;        // remap: n fastest -> coalesced out writes
        float* op = outP + ((size_t)b2 * N_ATOMS + (size_t)(blockIdx.x * 16 + n2)) * 3;
        op[0] = lds[n2 * 51 + b2 * 3 + 0];
        op[1] = lds[n2 * 51 + b2 * 3 + 1];
        op[2] = lds[n2 * 51 + b2 * 3 + 2];
    }
}

extern "C" void kernel_launch(void* const* d_in, const int* in_sizes, int n_in,
                              void* d_out, int out_size, void* d_ws, size_t ws_size,
                              hipStream_t stream) {
    const float* positions = (const float*)d_in[0];
    const int* bonds = (const int*)d_in[1];
    const float* W_msg = (const float*)d_in[2];
    const float* b_msg = (const float*)d_in[3];
    const float* W_upd = (const float*)d_in[4];
    const float* b_upd = (const float*)d_in[5];
    float* out = (float*)d_out;

    int* wsi = (int*)d_ws;
    int* deg = wsi + OFF_DEG;
    int* offsets = wsi + OFF_OFFSETS;
    int* cursor = wsi + OFF_CURSOR;
    int* adj = wsi + OFF_ADJ;
    float* Mc = (float*)(wsi + OFF_MC);
    float4* posT = (float4*)(wsi + OFF_POST);
    float4* h2T = (float4*)(wsi + OFF_H2T);

    // 1. zero degree (vectorized)
    zero_deg_kernel<<<(N_ATOMS / 4 + 255) / 256, 256, 0, stream>>>((int4*)deg);
    // 2. transpose positions -> posT  ||  degree count (independent, fused)
    deg_transpose_kernel<<<TRANS_BLOCKS + DEG_BLOCKS, 256, 0, stream>>>(bonds, deg, positions, posT);
    // 3. scan (block 0)  ||  Mc (block 1)
    scan_mc_kernel<<<2, 256, 0, stream>>>(deg, offsets, cursor, W_msg, b_msg, W_upd, Mc);
    // 4. adjacency fill
    fill_adj_kernel<<<(N_BONDS + 255) / 256, 256, 0, stream>>>(bonds, cursor, adj);
    // 5. iteration 1: posT -> h2T (node-major)
    gather_kernel<false><<<N_ATOMS / 16, 256, 0, stream>>>(posT, offsets, adj, Mc, b_upd, h2T, nullptr);
    // 6. iteration 2: h2T -> out[B][N][3] (LDS re-transpose)
    gather_kernel<true><<<N_ATOMS / 16, 256, 0, stream>>>(h2T, offsets, adj, Mc, b_upd, nullptr, out);
}

// Round 5
// 58.909 us; speedup vs baseline: 1.7316x; 1.7316x over previous
//
#include <hip/hip_runtime.h>

#define N_ATOMS 20000
#define BATCH   16
#define N_BONDS 60000
#define NDIR    (2 * N_BONDS)
#define NB      (N_ATOMS * BATCH)      // 320000

#define SCAN_BLOCKS 79                 // ceil(20000/256)

// Workspace layout (int-indexed):
//   deg[20000] | offsets[20001] | cursor[20000] | adj[120000] | partials[80]
//   Mc[12] floats | posT[N][16][4] floats | h2T same
#define OFF_DEG     0
#define OFF_OFFSETS 20000
#define OFF_CURSOR  40004
#define OFF_ADJ     60004
#define OFF_PART    180004
#define OFF_MC      180100
#define OFF_POST    180116                 // %4==0 -> 16B aligned
#define OFF_H2T     (OFF_POST + NB * 4)

#define TRANS_BLOCKS 1250   // 1250*256 = 320000 = N*B
#define DEG_BLOCKS   235    // ceil(60000/256)

// blocks [0,1250): transpose positions[B][N][3] -> posT[N][16][4] (b-fastest,
//                  256B-contiguous per node). blocks [1250,1485): degree count.
__global__ void deg_transpose_kernel(const int* __restrict__ bonds, int* __restrict__ deg,
                                     const float* __restrict__ pos, float4* __restrict__ posT) {
    int blk = blockIdx.x;
    if (blk < TRANS_BLOCKS) {
        int t = blk * 256 + threadIdx.x;        // 0..319999
        int b = t & 15, n = t >> 4;
        const float* p = pos + ((size_t)b * N_ATOMS + n) * 3;
        posT[n * 16 + b] = make_float4(p[0], p[1], p[2], 0.0f);
    } else {
        int e = (blk - TRANS_BLOCKS) * 256 + threadIdx.x;
        if (e < N_BONDS) {
            atomicAdd(&deg[bonds[2 * e]], 1);
            atomicAdd(&deg[bonds[2 * e + 1]], 1);
        }
    }
}

// blocks [0,79): chunk sums of deg -> partials.  block 79: Mc.
__global__ void partials_mc_kernel(const int* __restrict__ deg, int* __restrict__ partials,
                                   const float* __restrict__ W_msg, const float* __restrict__ b_msg,
                                   const float* __restrict__ W_upd, float* __restrict__ Mc) {
    int t = threadIdx.x;
    if (blockIdx.x == SCAN_BLOCKS) {
        if (t < 12) {
            float s = 0.0f;
            if (t < 9) {
                int i = t / 3, j = t % 3;
                for (int k = 0; k < 128; ++k) s += W_msg[i * 128 + k] * W_upd[k * 3 + j];
            } else {
                int j = t - 9;
                for (int k = 0; k < 128; ++k) s += b_msg[k] * W_upd[k * 3 + j];
            }
            Mc[t] = s;
        }
        return;
    }
    __shared__ int s[256];
    int i = blockIdx.x * 256 + t;
    s[t] = (i < N_ATOMS) ? deg[i] : 0;
    __syncthreads();
    for (int off = 128; off > 0; off >>= 1) {
        if (t < off) s[t] += s[t + off];
        __syncthreads();
    }
    if (t == 0) partials[blockIdx.x] = s[0];
}

// 79 blocks: block b scans its 256-chunk (LDS Hillis-Steele) + base from partials.
__global__ void scan_kernel(const int* __restrict__ deg, const int* __restrict__ partials,
                            int* __restrict__ offsets, int* __restrict__ cursor) {
    __shared__ int ps[SCAN_BLOCKS];
    __shared__ int s[256];
    int t = threadIdx.x;
    int i = blockIdx.x * 256 + t;
    if (t < SCAN_BLOCKS) ps[t] = partials[t];
    int v = (i < N_ATOMS) ? deg[i] : 0;
    s[t] = v;
    __syncthreads();
    // uniform base: LDS broadcast reads, all lanes same address
    int base = 0;
    for (int k = 0; k < blockIdx.x; ++k) base += ps[k];
    int acc = v;
    for (int off = 1; off < 256; off <<= 1) {
        int u = (t >= off) ? s[t - off] : 0;
        __syncthreads();
        acc += u;
        s[t] = acc;
        __syncthreads();
    }
    int excl = base + acc - v;
    if (i < N_ATOMS) {
        offsets[i] = excl;
        cursor[i] = excl;
        if (i == N_ATOMS - 1) offsets[N_ATOMS] = base + acc;
    }
}

__global__ void fill_adj_kernel(const int* __restrict__ bonds, int* __restrict__ cursor,
                                int* __restrict__ adj) {
    int e = blockIdx.x * blockDim.x + threadIdx.x;
    if (e >= N_BONDS) return;
    int a0 = bonds[2 * e];
    int a1 = bonds[2 * e + 1];
    int p1 = atomicAdd(&cursor[a1], 1);
    adj[p1] = a0;
    int p0 = atomicAdd(&cursor[a0], 1);
    adj[p0] = a1;
}

// Node-major fused iteration. Block = 16 nodes x 16 batches (b fastest): the 16
// lanes of a node-group gather the SAME neighbor j as one contiguous 256B read.
template <bool FINAL>
__global__ __launch_bounds__(256) void gather_kernel(const float4* __restrict__ hT,
                                                     const int* __restrict__ offsets,
                                                     const int* __restrict__ adj,
                                                     const float* __restrict__ Mc,
                                                     const float* __restrict__ b_upd,
                                                     float4* __restrict__ outT,
                                                     float* __restrict__ outP) {
    __shared__ float lds[16 * 51];           // stride 51: conflict-free re-transpose
    int t = threadIdx.x;
    int b = t & 15;
    int nl = t >> 4;
    int n = blockIdx.x * 16 + nl;            // 1250*16 = 20000 exactly
    int beg = offsets[n], end = offsets[n + 1];
    float sx = 0.0f, sy = 0.0f, sz = 0.0f;
    for (int k = beg; k < end; ++k) {
        int j = adj[k];                      // group-uniform -> broadcast
        float4 v = hT[j * 16 + b];           // 16 lanes = 256B contiguous
        sx += v.x; sy += v.y; sz += v.z;
    }
    float4 me = hT[n * 16 + b];
    int d = end - beg;
    float inv = d > 0 ? 1.0f / (float)d : 0.0f;
    float flag = d > 0 ? 1.0f : 0.0f;
    float o0 = me.x + inv * (sx * Mc[0] + sy * Mc[3] + sz * Mc[6]) + flag * Mc[9]  + b_upd[0];
    float o1 = me.y + inv * (sx * Mc[1] + sy * Mc[4] + sz * Mc[7]) + flag * Mc[10] + b_upd[1];
    float o2 = me.z + inv * (sx * Mc[2] + sy * Mc[5] + sz * Mc[8]) + flag * Mc[11] + b_upd[2];
    if (!FINAL) {
        outT[n * 16 + b] = make_float4(o0, o1, o2, 0.0f);
    } else {
        lds[nl * 51 + b * 3 + 0] = o0;
        lds[nl * 51 + b * 3 + 1] = o1;
        lds[nl * 51 + b * 3 + 2] = o2;
        __syncthreads();
        int b2 = t >> 4, n2 = t & 15;        // remap: n fastest -> coalesced writes
        float* op = outP + ((size_t)b2 * N_ATOMS + (size_t)(blockIdx.x * 16 + n2)) * 3;
        op[0] = lds[n2 * 51 + b2 * 3 + 0];
        op[1] = lds[n2 * 51 + b2 * 3 + 1];
        op[2] = lds[n2 * 51 + b2 * 3 + 2];
    }
}

extern "C" void kernel_launch(void* const* d_in, const int* in_sizes, int n_in,
                              void* d_out, int out_size, void* d_ws, size_t ws_size,
                              hipStream_t stream) {
    const float* positions = (const float*)d_in[0];
    const int* bonds = (const int*)d_in[1];
    const float* W_msg = (const float*)d_in[2];
    const float* b_msg = (const float*)d_in[3];
    const float* W_upd = (const float*)d_in[4];
    const float* b_upd = (const float*)d_in[5];
    float* out = (float*)d_out;

    int* wsi = (int*)d_ws;
    int* deg = wsi + OFF_DEG;
    int* offsets = wsi + OFF_OFFSETS;
    int* cursor = wsi + OFF_CURSOR;
    int* adj = wsi + OFF_ADJ;
    int* partials = wsi + OFF_PART;
    float* Mc = (float*)(wsi + OFF_MC);
    float4* posT = (float4*)(wsi + OFF_POST);
    float4* h2T = (float4*)(wsi + OFF_H2T);

    // 1. zero degree (driver fill, capture-legal)
    hipMemsetAsync(deg, 0, N_ATOMS * sizeof(int), stream);
    // 2. transpose positions -> posT  ||  degree count (fused)
    deg_transpose_kernel<<<TRANS_BLOCKS + DEG_BLOCKS, 256, 0, stream>>>(bonds, deg, positions, posT);
    // 3. chunk partial sums  ||  Mc
    partials_mc_kernel<<<SCAN_BLOCKS + 1, 256, 0, stream>>>(deg, partials, W_msg, b_msg, W_upd, Mc);
    // 4. multi-block exclusive scan -> offsets/cursor
    scan_kernel<<<SCAN_BLOCKS, 256, 0, stream>>>(deg, partials, offsets, cursor);
    // 5. adjacency fill
    fill_adj_kernel<<<(N_BONDS + 255) / 256, 256, 0, stream>>>(bonds, cursor, adj);
    // 6. iteration 1: posT -> h2T (node-major)
    gather_kernel<false><<<N_ATOMS / 16, 256, 0, stream>>>(posT, offsets, adj, Mc, b_upd, h2T, nullptr);
    // 7. iteration 2: h2T -> out[B][N][3] (LDS re-transpose)
    gather_kernel<true><<<N_ATOMS / 16, 256, 0, stream>>>(h2T, offsets, adj, Mc, b_upd, nullptr, out);
}